// Round 5
// baseline (911.324 us; speedup 1.0000x reference)
//
#include <hip/hip_runtime.h>
#include <hip/hip_bf16.h>
#include <stdint.h>

#define T_TOK 4096
#define DDIM  2048
#define HDIM  2048
#define NEXP  8
#define NPAIR (T_TOK * 4)
#define NT2   (DDIM / 64)   // 32 K-steps of 64

typedef __attribute__((ext_vector_type(8))) short bf16x8;
typedef __attribute__((ext_vector_type(4))) float f32x4;
typedef __attribute__((ext_vector_type(4))) unsigned short u16x4v;
typedef __attribute__((ext_vector_type(8))) unsigned short u16x8v;

__device__ inline unsigned short f2bf(float f) {
  unsigned u = __builtin_bit_cast(unsigned, f);
  unsigned r = (u + 0x7fffu + ((u >> 16) & 1u)) >> 16;
  return (unsigned short)r;
}

// ------- transpose + convert: [z][R=2048][C=2048] fp32 -> [z][C][R] bf16 -------
// z = 0..7 -> W1 expert z ; z = 8..15 -> W2 expert z-8. 64x64 fp32 tiles.
__global__ __launch_bounds__(256) void transpose_conv_kernel(const float* __restrict__ W1,
                                                             const float* __restrict__ W2,
                                                             unsigned short* __restrict__ W1t,
                                                             unsigned short* __restrict__ W2t) {
  __shared__ float tile[64][68];
  int z = blockIdx.z;
  const float* src = (z < 8 ? W1 : W2) + (size_t)(z & 7) * DDIM * HDIM;
  unsigned short* dst = (z < 8 ? W1t : W2t) + (size_t)(z & 7) * DDIM * HDIM;
  int c0 = blockIdx.x * 64, r0 = blockIdx.y * 64;
  int tid = threadIdx.x;
  // load: 4 rounds, each lane a float4
  int lr = tid >> 4, lcg = tid & 15;
#pragma unroll
  for (int i = 0; i < 4; ++i) {
    float4 v = *(const float4*)(src + (size_t)(r0 + lr + i * 16) * 2048 + c0 + lcg * 4);
    tile[lr + i * 16][lcg * 4]     = v.x;
    tile[lr + i * 16][lcg * 4 + 1] = v.y;
    tile[lr + i * 16][lcg * 4 + 2] = v.z;
    tile[lr + i * 16][lcg * 4 + 3] = v.w;
  }
  __syncthreads();
  // store: lane owns output row (c0+c), writes 16 consecutive r as 2x ushort8 (32B)
  int c = tid & 63, rg = tid >> 6;  // rg 0..3
  u16x8v o0, o1;
#pragma unroll
  for (int k = 0; k < 8; ++k) o0[k] = f2bf(tile[rg * 16 + k][c]);
#pragma unroll
  for (int k = 0; k < 8; ++k) o1[k] = f2bf(tile[rg * 16 + 8 + k][c]);
  unsigned short* drow = dst + (size_t)(c0 + c) * 2048 + r0 + rg * 16;
  *(u16x8v*)drow = o0;
  *(u16x8v*)(drow + 8) = o1;
}

// ---------------- routing (fused x->bf16 conversion) ----------------
__global__ __launch_bounds__(256) void routing_kernel(const float* __restrict__ x,
                                                      const float* __restrict__ Wg,
                                                      const float* __restrict__ bg,
                                                      float* __restrict__ logits,
                                                      float* __restrict__ rw,
                                                      int* __restrict__ sel,
                                                      int* __restrict__ cnt,
                                                      unsigned short* __restrict__ xb) {
  int t = blockIdx.x * 4 + (threadIdx.x >> 6);  // one wave per token
  int l = threadIdx.x & 63;
  const float* xr = x + (size_t)t * DDIM;
  float acc[8] = {0.f, 0.f, 0.f, 0.f, 0.f, 0.f, 0.f, 0.f};
#pragma unroll 1
  for (int i = 0; i < 8; ++i) {  // 8 iters x 256 floats/wave
    int d = i * 256 + l * 4;
    float4 xv = *(const float4*)(xr + d);
    u16x4v o;
    o[0] = f2bf(xv.x); o[1] = f2bf(xv.y); o[2] = f2bf(xv.z); o[3] = f2bf(xv.w);
    *(u16x4v*)(xb + (size_t)t * DDIM + d) = o;
    const float* wr = Wg + (size_t)d * 8;
    float xq[4] = {xv.x, xv.y, xv.z, xv.w};
#pragma unroll
    for (int q = 0; q < 4; ++q) {
      float4 w0 = *(const float4*)(wr + q * 8);
      float4 w1 = *(const float4*)(wr + q * 8 + 4);
      acc[0] = fmaf(xq[q], w0.x, acc[0]); acc[1] = fmaf(xq[q], w0.y, acc[1]);
      acc[2] = fmaf(xq[q], w0.z, acc[2]); acc[3] = fmaf(xq[q], w0.w, acc[3]);
      acc[4] = fmaf(xq[q], w1.x, acc[4]); acc[5] = fmaf(xq[q], w1.y, acc[5]);
      acc[6] = fmaf(xq[q], w1.z, acc[6]); acc[7] = fmaf(xq[q], w1.w, acc[7]);
    }
  }
#pragma unroll
  for (int e = 0; e < 8; ++e)
#pragma unroll
    for (int off = 32; off > 0; off >>= 1) acc[e] += __shfl_down(acc[e], off);
  if (l == 0) {
    float lg[8];
#pragma unroll
    for (int e = 0; e < 8; ++e) {
      lg[e] = acc[e] + bg[e];
      logits[(size_t)t * 8 + e] = lg[e];
    }
    float mx = lg[0];
#pragma unroll
    for (int e = 1; e < 8; ++e) mx = fmaxf(mx, lg[e]);
    float p[8];
#pragma unroll
    for (int e = 0; e < 8; ++e) p[e] = expf(lg[e] - mx);
    bool used[8] = {false, false, false, false, false, false, false, false};
    float wsum = 0.f; int se[4]; float pv[4];
    for (int k = 0; k < 4; ++k) {
      int best = 0; float bv = -1.f;
      for (int e = 0; e < 8; ++e)
        if (!used[e] && p[e] > bv) { bv = p[e]; best = e; }
      used[best] = true; se[k] = best; pv[k] = bv; wsum += bv;
    }
    for (int k = 0; k < 4; ++k) {
      rw[t * 4 + k] = pv[k] / wsum;
      sel[t * 4 + k] = se[k];
      atomicAdd(&cnt[se[k]], 1);
    }
  }
}

__global__ void offsets_kernel(const int* __restrict__ cnt, int* __restrict__ off) {
  if (threadIdx.x == 0) {
    int s = 0;
    for (int e = 0; e < NEXP; ++e) { off[e] = s; s += cnt[e]; }
  }
}

__global__ __launch_bounds__(256) void scatter_kernel(const int* __restrict__ sel,
                                                      const float* __restrict__ rw,
                                                      const int* __restrict__ off,
                                                      int* __restrict__ fill,
                                                      int* __restrict__ tok,
                                                      float* __restrict__ wof) {
  int t = blockIdx.x * 256 + threadIdx.x;
  for (int k = 0; k < 4; ++k) {
    int e = sel[t * 4 + k];
    int slot = atomicAdd(&fill[e], 1);
    int p = off[e] + slot;
    tok[p] = t;
    wof[p] = rw[t * 4 + k];
  }
}

// ---------------- MoE GEMM: m97 regime — 128x128 tile, BK=64, 4 waves, single-buffer LDS ----------------
#define GLL(g, l) __builtin_amdgcn_global_load_lds(                         \
    (const __attribute__((address_space(1))) void*)(g),                    \
    (__attribute__((address_space(3))) void*)(l), 16, 0, 0)

template <int MODE>
__global__ __launch_bounds__(256) void moe_gemm_kernel(
    const unsigned short* __restrict__ A, const unsigned short* __restrict__ Bt,
    const float* __restrict__ bias, const int* __restrict__ cnt,
    const int* __restrict__ off, const int* __restrict__ tok,
    const float* __restrict__ wof, unsigned short* __restrict__ hout,
    float* __restrict__ out) {
  __shared__ unsigned short lds[16384];  // 32 KiB: A [128][64] | B [128][64]
  const int bid = blockIdx.x;
  const int e   = bid & 7;        // expert == XCD (T1)
  const int rem = bid >> 3;
  const int bm  = rem & 31;       // 32 m-tiles (worst case ne=4096)
  const int bn  = rem >> 5;       // 16 n-tiles
  const int ne  = cnt[e];
  const int m0  = bm * 128;
  if (m0 >= ne) return;
  const int oe  = off[e];
  const int n0  = bn * 128;
  const int tid = threadIdx.x;
  const int w   = tid >> 6;
  const int l   = tid & 63;

  // staging: thread stages rows (tid>>3) + j*32 (j=0..3) for A and B, 16B chunks.
  // LDS linear; global source chunk XOR-swizzled (T2 both-sides; row&7 == (tid>>3)&7 for all j).
  const int srow = tid >> 3;                       // 0..31
  const int scg  = ((tid & 7) ^ (srow & 7)) * 8;   // swizzled source chunk, elems
  const unsigned short* aP[4];
  const unsigned short* bP[4];
#pragma unroll
  for (int j = 0; j < 4; ++j) {
    int r = m0 + j * 32 + srow;
    if (r > ne - 1) r = ne - 1;
    if (MODE == 0)
      aP[j] = A + (size_t)tok[oe + r] * 2048 + scg;
    else
      aP[j] = A + (size_t)(oe + r) * 2048 + scg;
    bP[j] = Bt + ((size_t)e * 2048 + n0 + j * 32 + srow) * 2048 + scg;
  }
  char* ldsc = (char*)lds;
  const int stDst = tid * 16;     // dest = base + j*4096 + tid*16 (wave-uniform base + lane*16)

  const int wr = (w >> 1) * 64;   // 2 waves in M
  const int wc = (w & 1) * 64;    // 2 waves in N
  const int lr = l & 15;
  const int lq = l >> 4;
  const int cx = lr & 7;
  const int wrlr = wr + lr;
  const int wclr = wc + lr;
  const int c0 = ((0 * 4 + lq) ^ cx) * 8;   // chunk offset (shorts) for kk=0
  const int c1 = ((1 * 4 + lq) ^ cx) * 8;   // kk=1

  const unsigned short* Ab = lds;          // [128][64]
  const unsigned short* Bb = lds + 8192;   // [128][64]

  f32x4 acc[4][4];
#pragma unroll
  for (int m = 0; m < 4; ++m)
#pragma unroll
    for (int n = 0; n < 4; ++n) acc[m][n] = (f32x4){0.f, 0.f, 0.f, 0.f};

#pragma unroll 1
  for (int t = 0; t < NT2; ++t) {
    const int k0 = t * 64;
#pragma unroll
    for (int j = 0; j < 4; ++j) GLL(aP[j] + k0, ldsc + j * 4096 + stDst);
#pragma unroll
    for (int j = 0; j < 4; ++j) GLL(bP[j] + k0, ldsc + 16384 + j * 4096 + stDst);
    __syncthreads();   // compiler drains vmcnt(0) before barrier -> tile ready

    bf16x8 af[4][2], bfr[4][2];
#pragma unroll
    for (int m = 0; m < 4; ++m) {
      af[m][0] = *(const bf16x8*)&Ab[(size_t)(wrlr + m * 16) * 64 + c0];
      af[m][1] = *(const bf16x8*)&Ab[(size_t)(wrlr + m * 16) * 64 + c1];
    }
#pragma unroll
    for (int n = 0; n < 4; ++n) {
      bfr[n][0] = *(const bf16x8*)&Bb[(size_t)(wclr + n * 16) * 64 + c0];
      bfr[n][1] = *(const bf16x8*)&Bb[(size_t)(wclr + n * 16) * 64 + c1];
    }
#pragma unroll
    for (int kk = 0; kk < 2; ++kk)
#pragma unroll
      for (int m = 0; m < 4; ++m)
#pragma unroll
        for (int n = 0; n < 4; ++n)
          acc[m][n] = __builtin_amdgcn_mfma_f32_16x16x32_bf16(af[m][kk], bfr[n][kk], acc[m][n], 0, 0, 0);
    __syncthreads();   // protect LDS overwrite next iteration
  }

  // epilogue: C/D layout col = lane&15, row = (lane>>4)*4 + j
  const int rj = lq * 4;
  float bvn[4];
#pragma unroll
  for (int n = 0; n < 4; ++n) bvn[n] = bias[e * 2048 + n0 + wc + n * 16 + lr];
#pragma unroll
  for (int m = 0; m < 4; ++m) {
    const int rbase = m0 + wr + m * 16 + rj;
#pragma unroll
    for (int j = 0; j < 4; ++j) {
      const int row = rbase + j;
      if (row < ne) {
        if (MODE == 0) {
#pragma unroll
          for (int n = 0; n < 4; ++n) {
            const int col = n0 + wc + n * 16 + lr;
            float v = acc[m][n][j] + bvn[n];
            float g = 0.5f * v * (1.0f + erff(v * 0.70710678118f));
            hout[(size_t)(oe + row) * 2048 + col] = f2bf(g);
          }
        } else {
          const int p = oe + row;
          const int tk = tok[p];
          const float wf = wof[p];
#pragma unroll
          for (int n = 0; n < 4; ++n) {
            const int col = n0 + wc + n * 16 + lr;
            atomicAdd(&out[(size_t)tk * 2048 + col], wf * (acc[m][n][j] + bvn[n]));
          }
        }
      }
    }
  }
}

extern "C" void kernel_launch(void* const* d_in, const int* in_sizes, int n_in,
                              void* d_out, int out_size, void* d_ws, size_t ws_size,
                              hipStream_t stream) {
  const float* x  = (const float*)d_in[0];
  const float* Wg = (const float*)d_in[1];
  const float* bg = (const float*)d_in[2];
  const float* W1 = (const float*)d_in[3];
  const float* b1 = (const float*)d_in[4];
  const float* W2 = (const float*)d_in[5];
  const float* b2 = (const float*)d_in[6];
  float* out = (float*)d_out;
  float* logits = out + (size_t)T_TOK * DDIM;

  char* ws = (char*)d_ws;
  int* cnt  = (int*)(ws);
  int* off  = (int*)(ws + 32);
  int* fill = (int*)(ws + 64);
  size_t o = 256;
  unsigned short* xb   = (unsigned short*)(ws + o); o += (size_t)T_TOK * DDIM * 2;
  unsigned short* W1t  = (unsigned short*)(ws + o); o += (size_t)NEXP * DDIM * HDIM * 2;
  unsigned short* W2t  = (unsigned short*)(ws + o); o += (size_t)NEXP * DDIM * HDIM * 2;
  unsigned short* hbuf = (unsigned short*)(ws + o); o += (size_t)NPAIR * HDIM * 2;
  float* rw  = (float*)(ws + o); o += (size_t)T_TOK * 4 * 4;
  int*   sel = (int*)(ws + o);   o += (size_t)T_TOK * 4 * 4;
  int*   tok = (int*)(ws + o);   o += (size_t)NPAIR * 4;
  float* wof = (float*)(ws + o); o += (size_t)NPAIR * 4;

  hipMemsetAsync(d_out, 0, (size_t)T_TOK * DDIM * sizeof(float), stream);
  hipMemsetAsync(ws, 0, 256, stream);

  transpose_conv_kernel<<<dim3(32, 32, 16), 256, 0, stream>>>(W1, W2, W1t, W2t);
  routing_kernel<<<T_TOK / 4, 256, 0, stream>>>(x, Wg, bg, logits, rw, sel, cnt, xb);
  offsets_kernel<<<1, 64, 0, stream>>>(cnt, off);
  scatter_kernel<<<T_TOK / 256, 256, 0, stream>>>(sel, rw, off, fill, tok, wof);

  moe_gemm_kernel<0><<<dim3(4096), 256, 0, stream>>>(xb, W1t, b1, cnt, off, tok, wof, hbuf, nullptr);
  moe_gemm_kernel<1><<<dim3(4096), 256, 0, stream>>>(hbuf, W2t, b2, cnt, off, tok, wof, nullptr, out);
}